// Round 9
// baseline (147.797 us; speedup 1.0000x reference)
//
#include <hip/hip_runtime.h>

// ---------------------------------------------------------------------------
// CVX_Reasoning_Engine — Round 9: async weight DMA (global_load_lds).
//   R4-R8 showed the kernel is bound by the L2 weight stream paid as
//   latency-exposed VGPR loads (occupancy/ILP changes were all neutral).
//   Now weights stream into LDS via fire-and-forget global_load_lds with
//   double-buffered k-chunks (m97 pattern); MFMA consumes from LDS.
//   512 thr/block, 32 rows, 134 KB LDS, 1 block/CU, grid 512.
// ---------------------------------------------------------------------------

#define MROWS 16384

typedef __attribute__((ext_vector_type(8))) short bf16x8;   // 8 bf16 = 4 VGPRs
typedef __attribute__((ext_vector_type(4))) float floatx4;

__device__ __forceinline__ unsigned short f2bf(float x) {
    union { float f; unsigned u; } c; c.f = x;
    unsigned r = c.u + 0x7fffu + ((c.u >> 16) & 1u);   // RNE
    return (unsigned short)(r >> 16);
}
__device__ __forceinline__ float bf2f(unsigned short b) {
    union { unsigned u; float f; } c; c.u = ((unsigned)b) << 16;
    return c.f;
}

// async 16B/lane global->LDS: wave moves 1 KB (one MFMA B-fragment).
__device__ __forceinline__ void dma16(const unsigned short* g, unsigned short* l, int lane) {
    __builtin_amdgcn_global_load_lds(
        (const __attribute__((address_space(1))) void*)(g + (size_t)lane * 8),
        (__attribute__((address_space(3))) void*)(l), 16, 0, 0);
}

// ---- pack W (KxN fp32) -> fragment-ordered bf16 (unchanged since R4) -------
__global__ __launch_bounds__(256) void pack_wt(
    const float* __restrict__ W1, unsigned short* __restrict__ T1,
    const float* __restrict__ W2, unsigned short* __restrict__ T2,
    const float* __restrict__ W3, unsigned short* __restrict__ T3,
    const float* __restrict__ W4, unsigned short* __restrict__ T4)
{
    const float* W; unsigned short* T; int Kreal, KS, nshift;
    switch (blockIdx.y) {
        case 0:  W = W1; T = T1; Kreal = 516; KS = 17; nshift = 9; break;
        case 1:  W = W2; T = T2; Kreal = 512; KS = 16; nshift = 8; break;
        case 2:  W = W3; T = T3; Kreal = 256; KS = 8;  nshift = 7; break;
        default: W = W4; T = T4; Kreal = 128; KS = 4;  nshift = 6; break;
    }
    const int N = 1 << nshift;
    const int idx = blockIdx.x * 256 + threadIdx.x;   // k*N + n over padded K
    if (idx >= N * KS * 32) return;
    const int k = idx >> nshift;
    const int n = idx & (N - 1);
    const unsigned short v = (k < Kreal) ? f2bf(W[idx]) : (unsigned short)0;
    const int ntile = n >> 4, m_l = n & 15;
    const int ks = k >> 5, quad = (k >> 3) & 3, e = k & 7;
    T[(size_t)(((ntile * KS + ks) * 64) + quad * 16 + m_l) * 8 + e] = v;
}

// ---- LDS layout (ushort element offsets) -----------------------------------
// zs 32x552 @0 (dead after L1; h2/h3/h4 overlay it):
//   h2 32x264 @0 ; h3 32x136 @8448 ; h4 32x72 @12800   (peak 15104 < 17664)
// h1 32x520 @17664 (dead after L2)
// wbuf 2 x 16384 @34304 (weight DMA double buffer, 32 KB each half)
// total 67,072 us = 134,144 B -> 1 block/CU.
#define OFF_ZS   0
#define LD_ZS    552
#define OFF_H1   17664
#define LD_H1    520
#define OFF_H2   0
#define LD_H2    264
#define OFF_H3   8448
#define LD_H3    136
#define OFF_H4   12800
#define LD_H4    72
#define OFF_WB   34304
#define WB_HALF  16384
#define LDS_TOT  67072

__global__ __launch_bounds__(512, 2) void fused_mlp_qp(
    const float* __restrict__ z, const float* __restrict__ bounds,
    const unsigned short* __restrict__ Wt1, const float* __restrict__ c1,
    const unsigned short* __restrict__ Wt2, const float* __restrict__ c2,
    const unsigned short* __restrict__ Wt3, const float* __restrict__ c3,
    const unsigned short* __restrict__ Wt4, const float* __restrict__ c4,
    const float* __restrict__ W5, const float* __restrict__ c5,
    float* __restrict__ out)
{
    __shared__ unsigned short lds[LDS_TOT];
    const int tid  = threadIdx.x;
    const int wid  = tid >> 6, lane = tid & 63;    // wid 0..7
    const int m_l  = lane & 15, quad = lane >> 4;
    const int bm   = blockIdx.x * 32;

    const float4 bnd = *(const float4*)bounds;

    // ---- issue L1 chunk 0 DMA first, then stage z (overlap) ----------------
    {
        unsigned short* dst = lds + OFF_WB;                 // buf0
        #pragma unroll
        for (int i = 0; i < 4; ++i) {
            const int nt = wid * 4 + i;
            dma16(Wt1 + (size_t)(nt * 17 + 0) * 64 * 8, dst + nt * 512, lane);
        }
    }
    {
        const float4* __restrict__ zf = (const float4*)(z + (size_t)bm * 512);
        #pragma unroll
        for (int i = 0; i < 8; ++i) {
            const int f   = i * 512 + tid;          // float4 idx in 32x128
            const int row = f >> 7, c4i = f & 127;
            const float4 v = zf[f];
            unsigned short t4[4] = {f2bf(v.x), f2bf(v.y), f2bf(v.z), f2bf(v.w)};
            *(uint2*)&lds[OFF_ZS + row * LD_ZS + c4i * 4] = *(uint2*)t4;
        }
        if (tid < 160) {   // cols 512..551: bounds then zeros
            const int row = tid / 5, j = tid % 5;
            unsigned short t8[8] = {0,0,0,0,0,0,0,0};
            if (j == 0) { t8[0] = f2bf(bnd.x); t8[1] = f2bf(bnd.y);
                          t8[2] = f2bf(bnd.z); t8[3] = f2bf(bnd.w); }
            *(uint4*)&lds[OFF_ZS + row * LD_ZS + 512 + j * 8] = *(uint4*)t8;
        }
    }
    __syncthreads();   // z staged + chunk0 drained

    // ================= Layer 1: 544 -> 512, NF=4, 17 k-chunks ===============
    {
        floatx4 acc[2][4];
        #pragma unroll
        for (int i = 0; i < 2; ++i)
            #pragma unroll
            for (int j = 0; j < 4; ++j) acc[i][j] = (floatx4){0.f,0.f,0.f,0.f};

        #pragma unroll
        for (int ks = 0; ks < 17; ++ks) {
            if (ks > 0) __syncthreads();                  // drains chunk ks DMA
            if (ks < 16) {                                // issue chunk ks+1
                unsigned short* dst = lds + OFF_WB + ((ks + 1) & 1) * WB_HALF;
                #pragma unroll
                for (int i = 0; i < 4; ++i) {
                    const int nt = wid * 4 + i;
                    dma16(Wt1 + (size_t)(nt * 17 + ks + 1) * 64 * 8, dst + nt * 512, lane);
                }
            }
            const unsigned short* wb = lds + OFF_WB + (ks & 1) * WB_HALF;
            const bf16x8 a0 = *(const bf16x8*)&lds[OFF_ZS + (m_l     ) * LD_ZS + ks*32 + quad*8];
            const bf16x8 a1 = *(const bf16x8*)&lds[OFF_ZS + (m_l + 16) * LD_ZS + ks*32 + quad*8];
            #pragma unroll
            for (int j = 0; j < 4; ++j) {
                const bf16x8 b = *(const bf16x8*)(wb + (wid * 4 + j) * 512 + lane * 8);
                acc[0][j] = __builtin_amdgcn_mfma_f32_16x16x32_bf16(a0, b, acc[0][j], 0, 0, 0);
                acc[1][j] = __builtin_amdgcn_mfma_f32_16x16x32_bf16(a1, b, acc[1][j], 0, 0, 0);
            }
        }
        // epilogue -> h1
        #pragma unroll
        for (int j = 0; j < 4; ++j) {
            const int col = wid * 64 + j * 16 + m_l;
            const float bv = c1[col];
            #pragma unroll
            for (int i = 0; i < 2; ++i)
                #pragma unroll
                for (int r = 0; r < 4; ++r) {
                    float v = acc[i][j][r] + bv;
                    v = v > 0.f ? v : 0.2f * v;
                    lds[OFF_H1 + (i*16 + quad*4 + r) * LD_H1 + col] = f2bf(v);
                }
        }
    }
    __syncthreads();   // h1 ready; wbuf free; zs reads done

    // ================= Layer 2: 512 -> 256, NF=2, 8 chunks of 2 ksteps ======
    {
        // issue chunk 0 (16 ntiles x 2 ks = 32 frags; 4 per wave)
        {
            unsigned short* dst = lds + OFF_WB;
            #pragma unroll
            for (int i = 0; i < 4; ++i) {
                const int nt = wid * 2 + (i >> 1), kl = i & 1;
                dma16(Wt2 + (size_t)(nt * 16 + kl) * 64 * 8, dst + (nt * 2 + kl) * 512, lane);
            }
        }
        __syncthreads();   // chunk0 drained

        floatx4 acc[2][2];
        #pragma unroll
        for (int i = 0; i < 2; ++i)
            #pragma unroll
            for (int j = 0; j < 2; ++j) acc[i][j] = (floatx4){0.f,0.f,0.f,0.f};

        #pragma unroll
        for (int c = 0; c < 8; ++c) {
            if (c > 0) __syncthreads();
            if (c < 7) {
                unsigned short* dst = lds + OFF_WB + ((c + 1) & 1) * WB_HALF;
                #pragma unroll
                for (int i = 0; i < 4; ++i) {
                    const int nt = wid * 2 + (i >> 1), kl = i & 1;
                    dma16(Wt2 + (size_t)(nt * 16 + (c + 1) * 2 + kl) * 64 * 8,
                          dst + (nt * 2 + kl) * 512, lane);
                }
            }
            const unsigned short* wb = lds + OFF_WB + (c & 1) * WB_HALF;
            #pragma unroll
            for (int kl = 0; kl < 2; ++kl) {
                const int ks = c * 2 + kl;
                const bf16x8 a0 = *(const bf16x8*)&lds[OFF_H1 + (m_l     ) * LD_H1 + ks*32 + quad*8];
                const bf16x8 a1 = *(const bf16x8*)&lds[OFF_H1 + (m_l + 16) * LD_H1 + ks*32 + quad*8];
                #pragma unroll
                for (int j = 0; j < 2; ++j) {
                    const bf16x8 b = *(const bf16x8*)(wb + ((wid*2 + j)*2 + kl)*512 + lane*8);
                    acc[0][j] = __builtin_amdgcn_mfma_f32_16x16x32_bf16(a0, b, acc[0][j], 0, 0, 0);
                    acc[1][j] = __builtin_amdgcn_mfma_f32_16x16x32_bf16(a1, b, acc[1][j], 0, 0, 0);
                }
            }
        }
        // epilogue -> h2 (overlays zs; all zs reads finished at L1-end barrier)
        #pragma unroll
        for (int j = 0; j < 2; ++j) {
            const int col = wid * 32 + j * 16 + m_l;
            const float bv = c2[col];
            #pragma unroll
            for (int i = 0; i < 2; ++i)
                #pragma unroll
                for (int r = 0; r < 4; ++r) {
                    float v = acc[i][j][r] + bv;
                    v = v > 0.f ? v : 0.2f * v;
                    lds[OFF_H2 + (i*16 + quad*4 + r) * LD_H2 + col] = f2bf(v);
                }
        }
    }
    __syncthreads();   // h2 ready; wbuf free

    // ================= Layer 3: 256 -> 128, whole Wt3 staged (64 KB) ========
    {
        #pragma unroll
        for (int i = 0; i < 8; ++i) {   // wave wid: ntile=wid, ks=i
            dma16(Wt3 + (size_t)(wid * 8 + i) * 64 * 8,
                  lds + OFF_WB + (wid * 8 + i) * 512, lane);
        }
        __syncthreads();   // Wt3 resident

        floatx4 acc[2];
        acc[0] = (floatx4){0.f,0.f,0.f,0.f};
        acc[1] = (floatx4){0.f,0.f,0.f,0.f};
        #pragma unroll
        for (int ks = 0; ks < 8; ++ks) {
            const bf16x8 a0 = *(const bf16x8*)&lds[OFF_H2 + (m_l     ) * LD_H2 + ks*32 + quad*8];
            const bf16x8 a1 = *(const bf16x8*)&lds[OFF_H2 + (m_l + 16) * LD_H2 + ks*32 + quad*8];
            const bf16x8 b  = *(const bf16x8*)(lds + OFF_WB + (wid * 8 + ks) * 512 + lane * 8);
            acc[0] = __builtin_amdgcn_mfma_f32_16x16x32_bf16(a0, b, acc[0], 0, 0, 0);
            acc[1] = __builtin_amdgcn_mfma_f32_16x16x32_bf16(a1, b, acc[1], 0, 0, 0);
        }
        const int col = wid * 16 + m_l;
        const float bv = c3[col];
        #pragma unroll
        for (int i = 0; i < 2; ++i)
            #pragma unroll
            for (int r = 0; r < 4; ++r) {
                float v = acc[i][r] + bv;
                v = v > 0.f ? v : 0.2f * v;
                lds[OFF_H3 + (i*16 + quad*4 + r) * LD_H3 + col] = f2bf(v);
            }
    }
    __syncthreads();   // h3 ready; wbuf free

    // ================= Layer 4: 128 -> 64, whole Wt4 staged (16 KB) =========
    {
        #pragma unroll
        for (int i = 0; i < 2; ++i) {   // flat frag f = wid*2+i: ntile=f>>2, ks=f&3
            const int f = wid * 2 + i;
            dma16(Wt4 + (size_t)f * 64 * 8, lds + OFF_WB + f * 512, lane);
        }
        __syncthreads();   // Wt4 resident

        const int wm4 = wid >> 2, wn4 = wid & 3;
        floatx4 acc4 = (floatx4){0.f,0.f,0.f,0.f};
        #pragma unroll
        for (int ks = 0; ks < 4; ++ks) {
            const bf16x8 a = *(const bf16x8*)&lds[OFF_H3 + (wm4*16 + m_l) * LD_H3 + ks*32 + quad*8];
            const bf16x8 b = *(const bf16x8*)(lds + OFF_WB + (wn4 * 4 + ks) * 512 + lane * 8);
            acc4 = __builtin_amdgcn_mfma_f32_16x16x32_bf16(a, b, acc4, 0, 0, 0);
        }
        const int col = wn4 * 16 + m_l;
        const float bv = c4[col];
        #pragma unroll
        for (int r = 0; r < 4; ++r) {
            float v = acc4[r] + bv;
            v = v > 0.f ? v : 0.2f * v;
            lds[OFF_H4 + (wm4*16 + quad*4 + r) * LD_H4 + col] = f2bf(v);
        }
    }
    __syncthreads();   // h4 ready

    // ================= Layer 5 (64->256 fp32) + QP ==========================
    const float4 cc = ((const float4*)c5)[lane];
    float ax[4], ay[4], aw[4], ah[4];
    #pragma unroll
    for (int r = 0; r < 4; ++r) { ax[r] = cc.x; ay[r] = cc.y; aw[r] = cc.z; ah[r] = cc.w; }
    const float4* __restrict__ W5v = (const float4*)W5;   // [k][64 objs]
    const int rbase = wid * 4;                            // 8 waves x 4 rows

    #pragma unroll 2
    for (int k4 = 0; k4 < 64; k4 += 4) {
        unsigned short hs[4][4];
        #pragma unroll
        for (int r = 0; r < 4; ++r) {
            const ushort4 t = *(const ushort4*)&lds[OFF_H4 + (rbase + r) * LD_H4 + k4];
            hs[r][0] = t.x; hs[r][1] = t.y; hs[r][2] = t.z; hs[r][3] = t.w;
        }
        #pragma unroll
        for (int kk = 0; kk < 4; ++kk) {
            const float4 w = W5v[(size_t)(k4 + kk) * 64 + lane];
            #pragma unroll
            for (int r = 0; r < 4; ++r) {
                const float h = bf2f(hs[r][kk]);
                ax[r] = fmaf(h, w.x, ax[r]);
                ay[r] = fmaf(h, w.y, ay[r]);
                aw[r] = fmaf(h, w.z, aw[r]);
                ah[r] = fmaf(h, w.w, ah[r]);
            }
        }
    }

    const float b0 = bnd.x, b1 = bnd.y, b2 = bnd.z, b3 = bnd.w;
    #pragma unroll
    for (int r = 0; r < 4; ++r) {
        float xs, wo, ys, ho;
        {
            const float px = ax[r], pw = aw[r];
            const float x0 = fmaxf(px, b0);
            const float g0 = fmaxf(pw, 1.0f);
            const float t  = 0.5f * (b2 - px - pw);
            const float xl = fminf(fmaxf(px + t, b0), b2 - 1.0f);
            const bool over = (x0 + g0) > b2;
            const float x = over ? xl : x0;
            const float g = over ? (b2 - xl) : g0;
            xs = x; wo = x + g;
        }
        {
            const float py = ay[r], ph = ah[r];
            const float x0 = fmaxf(py, b1);
            const float g0 = fmaxf(ph, 1.0f);
            const float t  = 0.5f * (b3 - py - ph);
            const float xl = fminf(fmaxf(py + t, b1), b3 - 1.0f);
            const bool over = (x0 + g0) > b3;
            const float x = over ? xl : x0;
            const float g = over ? (b3 - xl) : g0;
            ys = x; ho = x + g;
        }
        float4 o; o.x = xs; o.y = ys; o.z = wo; o.w = ho;
        ((float4*)out)[(size_t)(bm + rbase + r) * 64 + lane] = o;
    }
}

extern "C" void kernel_launch(void* const* d_in, const int* in_sizes, int n_in,
                              void* d_out, int out_size, void* d_ws, size_t ws_size,
                              hipStream_t stream) {
    const float* z      = (const float*)d_in[0];
    const float* bounds = (const float*)d_in[1];
    const float* W1 = (const float*)d_in[2];
    const float* c1 = (const float*)d_in[3];
    const float* W2 = (const float*)d_in[4];
    const float* c2 = (const float*)d_in[5];
    const float* W3 = (const float*)d_in[6];
    const float* c3 = (const float*)d_in[7];
    const float* W4 = (const float*)d_in[8];
    const float* c4 = (const float*)d_in[9];
    const float* W5 = (const float*)d_in[10];
    const float* c5 = (const float*)d_in[11];
    float* out = (float*)d_out;

    unsigned short* ws  = (unsigned short*)d_ws;
    unsigned short* Wt1 = ws;               // 512x544 = 278528
    unsigned short* Wt2 = Wt1 + 278528;     // 256x512 = 131072
    unsigned short* Wt3 = Wt2 + 131072;     // 128x256 = 32768
    unsigned short* Wt4 = Wt3 + 32768;      //  64x128 =  8192

    pack_wt<<<dim3(1088, 4), 256, 0, stream>>>(W1, Wt1, W2, Wt2, W3, Wt3, W4, Wt4);
    fused_mlp_qp<<<dim3(MROWS / 32), 512, 0, stream>>>(
        z, bounds, Wt1, c1, Wt2, c2, Wt3, c3, Wt4, c4, W5, c5, out);
}

// Round 10
// 128.713 us; speedup vs baseline: 1.1483x; 1.1483x over previous
//
#include <hip/hip_runtime.h>

// ---------------------------------------------------------------------------
// CVX_Reasoning_Engine — Round 10: R7 structure + MFMA layer-5.
//   L5 (64->256) moves from 2048 scalar fmaf/wave to 32 MFMA/wave using
//   split-bf16 W5 (hi+lo pair ~ fp32 precision). p round-trips through a
//   fp32 LDS buffer (stride 260, 16B-aligned rows) for the QP gather.
//   L1-L4 identical to R7 (best measured: 45 us fused).
// ---------------------------------------------------------------------------

#define MROWS 16384

typedef __attribute__((ext_vector_type(8))) short bf16x8;   // 8 bf16 = 4 VGPRs
typedef __attribute__((ext_vector_type(4))) float floatx4;

__device__ __forceinline__ unsigned short f2bf(float x) {
    union { float f; unsigned u; } c; c.f = x;
    unsigned r = c.u + 0x7fffu + ((c.u >> 16) & 1u);   // RNE
    return (unsigned short)(r >> 16);
}
__device__ __forceinline__ float bf2f(unsigned short b) {
    union { unsigned u; float f; } c; c.u = ((unsigned)b) << 16;
    return c.f;
}

// ---- pack weights -> fragment-ordered bf16 ---------------------------------
// Cases 0-3: W1..W4 single bf16. Case 4: W5 split into hi+lo bf16 pair.
// T[((ntile*KS + ks)*64 + quad*16 + m_l)*8 + e] = W[k][n],
//   n = ntile*16 + m_l, k = ks*32 + quad*8 + e.
__global__ __launch_bounds__(256) void pack_wt(
    const float* __restrict__ W1, unsigned short* __restrict__ T1,
    const float* __restrict__ W2, unsigned short* __restrict__ T2,
    const float* __restrict__ W3, unsigned short* __restrict__ T3,
    const float* __restrict__ W4, unsigned short* __restrict__ T4,
    const float* __restrict__ W5, unsigned short* __restrict__ T5h,
    unsigned short* __restrict__ T5l)
{
    const int idx = blockIdx.x * 256 + threadIdx.x;
    if (blockIdx.y == 4) {            // W5: K=64, N=256, KS=2, split hi/lo
        if (idx >= 256 * 64) return;
        const int k = idx >> 8, n = idx & 255;
        const float v = W5[idx];
        const unsigned short hi = f2bf(v);
        const unsigned short lo = f2bf(v - bf2f(hi));
        const int ntile = n >> 4, m_l = n & 15;
        const int ks = k >> 5, quad = (k >> 3) & 3, e = k & 7;
        const size_t o = (size_t)(((ntile * 2 + ks) * 64) + quad * 16 + m_l) * 8 + e;
        T5h[o] = hi; T5l[o] = lo;
        return;
    }
    const float* W; unsigned short* T; int Kreal, KS, nshift;
    switch (blockIdx.y) {
        case 0:  W = W1; T = T1; Kreal = 516; KS = 17; nshift = 9; break;
        case 1:  W = W2; T = T2; Kreal = 512; KS = 16; nshift = 8; break;
        case 2:  W = W3; T = T3; Kreal = 256; KS = 8;  nshift = 7; break;
        default: W = W4; T = T4; Kreal = 128; KS = 4;  nshift = 6; break;
    }
    const int N = 1 << nshift;
    if (idx >= N * KS * 32) return;
    const int k = idx >> nshift;
    const int n = idx & (N - 1);
    const unsigned short v = (k < Kreal) ? f2bf(W[idx]) : (unsigned short)0;
    const int ntile = n >> 4, m_l = n & 15;
    const int ks = k >> 5, quad = (k >> 3) & 3, e = k & 7;
    T[(size_t)(((ntile * KS + ks) * 64) + quad * 16 + m_l) * 8 + e] = v;
}

// ---- LDS layout (ushort element offsets) — R7 + p32 buffer ------------------
// Region A [0,17664): zs 32x552. After L1: h2 32x264 @0, h4 32x72 @8448.
// Region B [17664,34304): h1 32x520. After L2: h3 32x136 @17664.
//   After L4: p32 = fp32 32x260 @17664 (byte 35328, 16B aligned; fits exactly).
#define OFF_ZS   0
#define LD_ZS    552
#define OFF_H1   17664
#define LD_H1    520
#define OFF_H2   0
#define LD_H2    264
#define OFF_H3   17664
#define LD_H3    136
#define OFF_H4   8448
#define LD_H4    72
#define OFF_P    17664
#define LD_P     260
#define LDS_TOT  34304

// generic MFMA layer: C[32xN] = lrelu(A[32xK] @ W^T + bias), barrier-free.
template<int NF, int KSTEPS>
__device__ __forceinline__ void layer_gemm(
    unsigned short* lds, int offA, int lda, int offC, int ldc,
    const unsigned short* __restrict__ Wt,
    const float* __restrict__ bias, int wid, int lane)
{
    const int m_l = lane & 15, quad = lane >> 4;
    const unsigned short* __restrict__ Wl =
        Wt + ((size_t)(wid * NF) * KSTEPS * 64 + lane) * 8;
    floatx4 acc[2][NF];
    #pragma unroll
    for (int i = 0; i < 2; ++i)
        #pragma unroll
        for (int j = 0; j < NF; ++j)
            acc[i][j] = (floatx4){0.f, 0.f, 0.f, 0.f};

    #pragma unroll
    for (int ks = 0; ks < KSTEPS; ++ks) {
        const bf16x8 a0 = *(const bf16x8*)&lds[offA + (m_l     ) * lda + ks*32 + quad*8];
        const bf16x8 a1 = *(const bf16x8*)&lds[offA + (m_l + 16) * lda + ks*32 + quad*8];
        #pragma unroll
        for (int j = 0; j < NF; ++j) {
            const bf16x8 b = *(const bf16x8*)(Wl + (size_t)(j * KSTEPS + ks) * 512);
            acc[0][j] = __builtin_amdgcn_mfma_f32_16x16x32_bf16(a0, b, acc[0][j], 0, 0, 0);
            acc[1][j] = __builtin_amdgcn_mfma_f32_16x16x32_bf16(a1, b, acc[1][j], 0, 0, 0);
        }
    }
    #pragma unroll
    for (int j = 0; j < NF; ++j) {
        const int col = wid * (NF * 16) + j * 16 + m_l;
        const float bv = bias[col];
        #pragma unroll
        for (int i = 0; i < 2; ++i)
            #pragma unroll
            for (int r = 0; r < 4; ++r) {
                float v = acc[i][j][r] + bv;
                v = v > 0.f ? v : 0.2f * v;
                lds[offC + (i*16 + quad*4 + r) * ldc + col] = f2bf(v);
            }
    }
}

__global__ __launch_bounds__(256, 2) void fused_mlp_qp(
    const float* __restrict__ z, const float* __restrict__ bounds,
    const unsigned short* __restrict__ Wt1, const float* __restrict__ c1,
    const unsigned short* __restrict__ Wt2, const float* __restrict__ c2,
    const unsigned short* __restrict__ Wt3, const float* __restrict__ c3,
    const unsigned short* __restrict__ Wt4, const float* __restrict__ c4,
    const unsigned short* __restrict__ Wt5h, const unsigned short* __restrict__ Wt5l,
    const float* __restrict__ c5,
    float* __restrict__ out)
{
    __shared__ unsigned short lds[LDS_TOT];
    const int tid  = threadIdx.x;
    const int wid  = tid >> 6, lane = tid & 63;    // wid 0..3
    const int m_l  = lane & 15, quad = lane >> 4;
    const int bm   = blockIdx.x * 32;

    const float4 bnd = *(const float4*)bounds;

    // ---- stage ALL of z for this block (one latency, then barrier) ---------
    {
        const float4* __restrict__ zf = (const float4*)(z + (size_t)bm * 512);
        #pragma unroll
        for (int i = 0; i < 16; ++i) {
            const int f   = i * 256 + tid;          // float4 idx in 32x128
            const int row = f >> 7, c4i = f & 127;
            const float4 v = zf[f];
            unsigned short t4[4] = {f2bf(v.x), f2bf(v.y), f2bf(v.z), f2bf(v.w)};
            *(uint2*)&lds[OFF_ZS + row * LD_ZS + c4i * 4] = *(uint2*)t4;
        }
        if (tid < 160) {   // cols 512..551: bounds then zeros
            const int row = tid / 5, j = tid % 5;
            unsigned short t8[8] = {0,0,0,0,0,0,0,0};
            if (j == 0) { t8[0] = f2bf(bnd.x); t8[1] = f2bf(bnd.y);
                          t8[2] = f2bf(bnd.z); t8[3] = f2bf(bnd.w); }
            *(uint4*)&lds[OFF_ZS + row * LD_ZS + 512 + j * 8] = *(uint4*)t8;
        }
    }
    __syncthreads();

    // ---- MFMA layers 1-4 (barrier-free inside; R7 verbatim) ----------------
    layer_gemm<8,17>(lds, OFF_ZS, LD_ZS, OFF_H1, LD_H1, Wt1, c1, wid, lane);
    __syncthreads();
    layer_gemm<4,16>(lds, OFF_H1, LD_H1, OFF_H2, LD_H2, Wt2, c2, wid, lane);
    __syncthreads();
    layer_gemm<2,8 >(lds, OFF_H2, LD_H2, OFF_H3, LD_H3, Wt3, c3, wid, lane);
    __syncthreads();
    layer_gemm<1,4 >(lds, OFF_H3, LD_H3, OFF_H4, LD_H4, Wt4, c4, wid, lane);
    __syncthreads();

    // ---- Layer 5 via MFMA: N=256, K=64, NF=4, KS=2, split-bf16 W5 ----------
    {
        const size_t wb = ((size_t)(wid * 4) * 2 * 64 + lane) * 8;
        const unsigned short* __restrict__ Wh = Wt5h + wb;
        const unsigned short* __restrict__ Wl = Wt5l + wb;
        floatx4 acc[2][4];
        #pragma unroll
        for (int i = 0; i < 2; ++i)
            #pragma unroll
            for (int j = 0; j < 4; ++j) acc[i][j] = (floatx4){0.f,0.f,0.f,0.f};

        #pragma unroll
        for (int ks = 0; ks < 2; ++ks) {
            const bf16x8 a0 = *(const bf16x8*)&lds[OFF_H4 + (m_l     ) * LD_H4 + ks*32 + quad*8];
            const bf16x8 a1 = *(const bf16x8*)&lds[OFF_H4 + (m_l + 16) * LD_H4 + ks*32 + quad*8];
            #pragma unroll
            for (int j = 0; j < 4; ++j) {
                const bf16x8 bh = *(const bf16x8*)(Wh + (size_t)(j * 2 + ks) * 512);
                const bf16x8 bl = *(const bf16x8*)(Wl + (size_t)(j * 2 + ks) * 512);
                acc[0][j] = __builtin_amdgcn_mfma_f32_16x16x32_bf16(a0, bh, acc[0][j], 0, 0, 0);
                acc[0][j] = __builtin_amdgcn_mfma_f32_16x16x32_bf16(a0, bl, acc[0][j], 0, 0, 0);
                acc[1][j] = __builtin_amdgcn_mfma_f32_16x16x32_bf16(a1, bh, acc[1][j], 0, 0, 0);
                acc[1][j] = __builtin_amdgcn_mfma_f32_16x16x32_bf16(a1, bl, acc[1][j], 0, 0, 0);
            }
        }
        // epilogue: + c5, store fp32 p to LDS (2-way banks; verified layout)
        float* __restrict__ p = (float*)&lds[OFF_P];
        #pragma unroll
        for (int j = 0; j < 4; ++j) {
            const int col = wid * 64 + j * 16 + m_l;
            const float bv = c5[col];
            #pragma unroll
            for (int i = 0; i < 2; ++i)
                #pragma unroll
                for (int r = 0; r < 4; ++r)
                    p[(i*16 + quad*4 + r) * LD_P + col] = acc[i][j][r] + bv;
        }
    }
    __syncthreads();

    // ---- QP: one row per wave-iteration, contiguous float4 LDS reads -------
    const float b0 = bnd.x, b1 = bnd.y, b2 = bnd.z, b3 = bnd.w;
    const float* __restrict__ p = (const float*)&lds[OFF_P];
    #pragma unroll
    for (int i = 0; i < 8; ++i) {
        const int row = i * 4 + wid;                 // 0..31, uniform per wave
        const float4 pv = *(const float4*)&p[row * LD_P + lane * 4];
        float xs, wo, ys, ho;
        {
            const float px = pv.x, pw = pv.z;
            const float x0 = fmaxf(px, b0);
            const float g0 = fmaxf(pw, 1.0f);
            const float t  = 0.5f * (b2 - px - pw);
            const float xl = fminf(fmaxf(px + t, b0), b2 - 1.0f);
            const bool over = (x0 + g0) > b2;
            const float x = over ? xl : x0;
            const float g = over ? (b2 - xl) : g0;
            xs = x; wo = x + g;
        }
        {
            const float py = pv.y, ph = pv.w;
            const float x0 = fmaxf(py, b1);
            const float g0 = fmaxf(ph, 1.0f);
            const float t  = 0.5f * (b3 - py - ph);
            const float xl = fminf(fmaxf(py + t, b1), b3 - 1.0f);
            const bool over = (x0 + g0) > b3;
            const float x = over ? xl : x0;
            const float g = over ? (b3 - xl) : g0;
            ys = x; ho = x + g;
        }
        float4 o; o.x = xs; o.y = ys; o.z = wo; o.w = ho;
        ((float4*)out)[(size_t)(bm + row) * 64 + lane] = o;
    }
}

extern "C" void kernel_launch(void* const* d_in, const int* in_sizes, int n_in,
                              void* d_out, int out_size, void* d_ws, size_t ws_size,
                              hipStream_t stream) {
    const float* z      = (const float*)d_in[0];
    const float* bounds = (const float*)d_in[1];
    const float* W1 = (const float*)d_in[2];
    const float* c1 = (const float*)d_in[3];
    const float* W2 = (const float*)d_in[4];
    const float* c2 = (const float*)d_in[5];
    const float* W3 = (const float*)d_in[6];
    const float* c3 = (const float*)d_in[7];
    const float* W4 = (const float*)d_in[8];
    const float* c4 = (const float*)d_in[9];
    const float* W5 = (const float*)d_in[10];
    const float* c5 = (const float*)d_in[11];
    float* out = (float*)d_out;

    unsigned short* ws   = (unsigned short*)d_ws;
    unsigned short* Wt1  = ws;                // 512x544 = 278528
    unsigned short* Wt2  = Wt1 + 278528;      // 256x512 = 131072
    unsigned short* Wt3  = Wt2 + 131072;      // 128x256 = 32768
    unsigned short* Wt4  = Wt3 + 32768;       //  64x128 =  8192
    unsigned short* Wt5h = Wt4 + 8192;        // 256x64  = 16384
    unsigned short* Wt5l = Wt5h + 16384;      // 256x64  = 16384

    pack_wt<<<dim3(1088, 5), 256, 0, stream>>>(
        W1, Wt1, W2, Wt2, W3, Wt3, W4, Wt4, W5, Wt5h, Wt5l);
    fused_mlp_qp<<<dim3(MROWS / 32), 256, 0, stream>>>(
        z, bounds, Wt1, c1, Wt2, c2, Wt3, c3, Wt4, c4, Wt5h, Wt5l, c5, out);
}

// Round 11
// 124.315 us; speedup vs baseline: 1.1889x; 1.0354x over previous
//
#include <hip/hip_runtime.h>

// ---------------------------------------------------------------------------
// CVX_Reasoning_Engine — Round 11: asm-pipelined weight stream.
//   R4-R10 proved the compiler never keeps >1 B-fragment load in flight
//   (time ≈ Σ serialized L2 latencies; immune to TLP/traffic/DMA changes).
//   Fix: issue fragment loads via asm volatile global_load_dwordx4 into an
//   8-deep register ring, consume behind explicit `s_waitcnt vmcnt(7)` asm
//   with the data threaded through (+v) so the backend can neither see,
//   sink, nor drain the pipeline. Packing is ks-major = wave stream order.
//   Biases folded into acc init (no in-loop compiler vmem => exact vmcnt).
// ---------------------------------------------------------------------------

#define MROWS 16384

typedef __attribute__((ext_vector_type(8))) short bf16x8;   // 8 bf16 = 4 VGPRs
typedef __attribute__((ext_vector_type(4))) float floatx4;

__device__ __forceinline__ unsigned short f2bf(float x) {
    union { float f; unsigned u; } c; c.f = x;
    unsigned r = c.u + 0x7fffu + ((c.u >> 16) & 1u);   // RNE
    return (unsigned short)(r >> 16);
}
__device__ __forceinline__ float bf2f(unsigned short b) {
    union { unsigned u; float f; } c; c.u = ((unsigned)b) << 16;
    return c.f;
}

// --- invisible-to-compiler 16B global load (1 KB/wave) ----------------------
__device__ __forceinline__ bf16x8 gload(const unsigned short* p) {
    bf16x8 r;
    asm volatile("global_load_dwordx4 %0, %1, off"
                 : "=&v"(r)
                 : "v"((unsigned long long)(size_t)p)
                 : "memory");
    return r;
}
// wait until <=IMM vmem outstanding; ties v so consumers can't hoist above.
template<int IMM>
__device__ __forceinline__ void vwait(bf16x8& v) {
    asm volatile("s_waitcnt vmcnt(%1)" : "+v"(v) : "n"(IMM) : "memory");
}
__device__ __forceinline__ void drain8(bf16x8 (&r)[8]) {
    asm volatile("s_waitcnt vmcnt(0)"
                 : "+v"(r[0]), "+v"(r[1]), "+v"(r[2]), "+v"(r[3]),
                   "+v"(r[4]), "+v"(r[5]), "+v"(r[6]), "+v"(r[7])
                 :: "memory");
}
__device__ __forceinline__ void drain4(bf16x8 (&r)[4]) {
    asm volatile("s_waitcnt vmcnt(0)"
                 : "+v"(r[0]), "+v"(r[1]), "+v"(r[2]), "+v"(r[3])
                 :: "memory");
}

// ---- pack weights -> ks-major fragment-ordered bf16 ------------------------
// W1..W4: T[((ks*NT + ntile)*64 + quad*16 + m_l)*8 + e],  NT = N/16.
// W5: split hi/lo interleaved: T5[(((ks*16 + ntile)*2 + hl)*64 + ...)*8 + e].
__global__ __launch_bounds__(256) void pack_wt(
    const float* __restrict__ W1, unsigned short* __restrict__ T1,
    const float* __restrict__ W2, unsigned short* __restrict__ T2,
    const float* __restrict__ W3, unsigned short* __restrict__ T3,
    const float* __restrict__ W4, unsigned short* __restrict__ T4,
    const float* __restrict__ W5, unsigned short* __restrict__ T5)
{
    const int idx = blockIdx.x * 256 + threadIdx.x;
    if (blockIdx.y == 4) {            // W5: K=64, N=256 -> NT=16, KS=2
        if (idx >= 256 * 64) return;
        const int k = idx >> 8, n = idx & 255;
        const float v = W5[idx];
        const unsigned short hi = f2bf(v);
        const unsigned short lo = f2bf(v - bf2f(hi));
        const int ntile = n >> 4, m_l = n & 15;
        const int ks = k >> 5, quad = (k >> 3) & 3, e = k & 7;
        const size_t b = (size_t)(((ks * 16 + ntile) * 2) * 64 + quad * 16 + m_l) * 8 + e;
        T5[b] = hi; T5[b + 512] = lo;
        return;
    }
    const float* W; unsigned short* T; int Kreal, nshift;
    switch (blockIdx.y) {
        case 0:  W = W1; T = T1; Kreal = 516; nshift = 9; break;
        case 1:  W = W2; T = T2; Kreal = 512; nshift = 8; break;
        case 2:  W = W3; T = T3; Kreal = 256; nshift = 7; break;
        default: W = W4; T = T4; Kreal = 128; nshift = 6; break;
    }
    const int N = 1 << nshift, NT = N >> 4;
    const int KS = (Kreal + 31) >> 5;
    if (idx >= N * KS * 32) return;
    const int k = idx >> nshift;
    const int n = idx & (N - 1);
    const unsigned short v = (k < Kreal) ? f2bf(W[idx]) : (unsigned short)0;
    const int ntile = n >> 4, m_l = n & 15;
    const int ks = k >> 5, quad = (k >> 3) & 3, e = k & 7;
    T[(size_t)((ks * NT + ntile) * 64 + quad * 16 + m_l) * 8 + e] = v;
}

// ---- LDS layout — identical to R10 ------------------------------------------
#define OFF_ZS   0
#define LD_ZS    552
#define OFF_H1   17664
#define LD_H1    520
#define OFF_H2   0
#define LD_H2    264
#define OFF_H3   17664
#define LD_H3    136
#define OFF_H4   8448
#define LD_H4    72
#define OFF_P    17664
#define LD_P     260
#define LDS_TOT  34304

// streamed MFMA layer: C[32xN] = lrelu(A[32xK] @ W^T + bias).
// ks-major packed Wt; DEP-deep asm load pipeline; bias pre-folded into acc.
template<int NF, int KSTEPS, int NT, int DEP>
__device__ __forceinline__ void layer_stream(
    unsigned short* lds, int offA, int lda, int offC, int ldc,
    const unsigned short* __restrict__ Wt,
    const float* __restrict__ bias, int wid, int lane)
{
    const int m_l = lane & 15, quad = lane >> 4;
    constexpr int NFR = NF * KSTEPS;
    const unsigned short* __restrict__ Wb = Wt + ((size_t)(wid * NF) * 64 + lane) * 8;

    floatx4 acc[2][NF];
    #pragma unroll
    for (int j = 0; j < NF; ++j) {
        const float bv = bias[wid * (NF * 16) + j * 16 + m_l];
        acc[0][j] = (floatx4){bv, bv, bv, bv};
        acc[1][j] = (floatx4){bv, bv, bv, bv};
    }

    bf16x8 ring[DEP];
    #pragma unroll
    for (int f = 0; f < DEP; ++f) {
        const int g = (f < NFR) ? f : 0;
        ring[f] = gload(Wb + (size_t)((g / NF) * NT + (g % NF)) * 512);
    }
    bf16x8 a0, a1;
    #pragma unroll
    for (int f = 0; f < NFR; ++f) {
        const int ks = f / NF, j = f - ks * NF;
        if (j == 0) {
            a0 = *(const bf16x8*)&lds[offA + (m_l     ) * lda + ks*32 + quad*8];
            a1 = *(const bf16x8*)&lds[offA + (m_l + 16) * lda + ks*32 + quad*8];
        }
        vwait<DEP - 1>(ring[f % DEP]);
        acc[0][j] = __builtin_amdgcn_mfma_f32_16x16x32_bf16(a0, ring[f % DEP], acc[0][j], 0, 0, 0);
        acc[1][j] = __builtin_amdgcn_mfma_f32_16x16x32_bf16(a1, ring[f % DEP], acc[1][j], 0, 0, 0);
        const int nf2 = (f + DEP < NFR) ? f + DEP : 0;   // tail: dummy re-issues
        ring[f % DEP] = gload(Wb + (size_t)((nf2 / NF) * NT + (nf2 % NF)) * 512);
    }
    if constexpr (DEP == 8) drain8(ring); else drain4(ring);

    // epilogue: lrelu -> bf16 LDS (bias already in acc)
    #pragma unroll
    for (int j = 0; j < NF; ++j) {
        const int col = wid * (NF * 16) + j * 16 + m_l;
        #pragma unroll
        for (int i = 0; i < 2; ++i)
            #pragma unroll
            for (int r = 0; r < 4; ++r) {
                float v = acc[i][j][r];
                v = v > 0.f ? v : 0.2f * v;
                lds[offC + (i*16 + quad*4 + r) * ldc + col] = f2bf(v);
            }
    }
}

__global__ __launch_bounds__(256, 2) void fused_mlp_qp(
    const float* __restrict__ z, const float* __restrict__ bounds,
    const unsigned short* __restrict__ Wt1, const float* __restrict__ c1,
    const unsigned short* __restrict__ Wt2, const float* __restrict__ c2,
    const unsigned short* __restrict__ Wt3, const float* __restrict__ c3,
    const unsigned short* __restrict__ Wt4, const float* __restrict__ c4,
    const unsigned short* __restrict__ Wt5, const float* __restrict__ c5,
    float* __restrict__ out)
{
    __shared__ unsigned short lds[LDS_TOT];
    const int tid  = threadIdx.x;
    const int wid  = tid >> 6, lane = tid & 63;    // wid 0..3
    const int m_l  = lane & 15, quad = lane >> 4;
    const int bm   = blockIdx.x * 32;

    const float4 bnd = *(const float4*)bounds;

    // ---- stage ALL of z (one latency; barrier drains everything) -----------
    {
        const float4* __restrict__ zf = (const float4*)(z + (size_t)bm * 512);
        #pragma unroll
        for (int i = 0; i < 16; ++i) {
            const int f   = i * 256 + tid;
            const int row = f >> 7, c4i = f & 127;
            const float4 v = zf[f];
            unsigned short t4[4] = {f2bf(v.x), f2bf(v.y), f2bf(v.z), f2bf(v.w)};
            *(uint2*)&lds[OFF_ZS + row * LD_ZS + c4i * 4] = *(uint2*)t4;
        }
        if (tid < 160) {   // cols 512..551: bounds then zeros
            const int row = tid / 5, j = tid % 5;
            unsigned short t8[8] = {0,0,0,0,0,0,0,0};
            if (j == 0) { t8[0] = f2bf(bnd.x); t8[1] = f2bf(bnd.y);
                          t8[2] = f2bf(bnd.z); t8[3] = f2bf(bnd.w); }
            *(uint4*)&lds[OFF_ZS + row * LD_ZS + 512 + j * 8] = *(uint4*)t8;
        }
    }
    __syncthreads();

    // ---- streamed MFMA layers 1-4 ------------------------------------------
    layer_stream<8,17,32,8>(lds, OFF_ZS, LD_ZS, OFF_H1, LD_H1, Wt1, c1, wid, lane);
    __syncthreads();
    layer_stream<4,16,16,8>(lds, OFF_H1, LD_H1, OFF_H2, LD_H2, Wt2, c2, wid, lane);
    __syncthreads();
    layer_stream<2,8, 8, 8>(lds, OFF_H2, LD_H2, OFF_H3, LD_H3, Wt3, c3, wid, lane);
    __syncthreads();
    layer_stream<1,4, 4, 4>(lds, OFF_H3, LD_H3, OFF_H4, LD_H4, Wt4, c4, wid, lane);
    __syncthreads();

    // ---- Layer 5: split-bf16 W5 stream (NFR=16: ks(2) x j(4) x {hi,lo}) ----
    {
        const unsigned short* __restrict__ Wb5 = Wt5 + (size_t)wid * 4096 + (size_t)lane * 8;
        floatx4 acc[2][4];
        #pragma unroll
        for (int j = 0; j < 4; ++j) {
            const float bv = c5[wid * 64 + j * 16 + m_l];
            acc[0][j] = (floatx4){bv, bv, bv, bv};
            acc[1][j] = (floatx4){bv, bv, bv, bv};
        }
        auto w5off = [](int g) {   // g = ((ks*4 + j)*2 + hl) local to wave
            const int ks = g >> 3, rem = g & 7;
            return (size_t)ks * 16384 + (size_t)(rem >> 1) * 1024 + (size_t)(rem & 1) * 512;
        };
        bf16x8 ring[8];
        #pragma unroll
        for (int f = 0; f < 8; ++f) ring[f] = gload(Wb5 + w5off(f));
        bf16x8 a0, a1;
        #pragma unroll
        for (int f = 0; f < 16; ++f) {
            const int ks = f >> 3, rem = f & 7, j = rem >> 1;
            if (rem == 0) {
                a0 = *(const bf16x8*)&lds[OFF_H4 + (m_l     ) * LD_H4 + ks*32 + quad*8];
                a1 = *(const bf16x8*)&lds[OFF_H4 + (m_l + 16) * LD_H4 + ks*32 + quad*8];
            }
            vwait<7>(ring[f & 7]);
            acc[0][j] = __builtin_amdgcn_mfma_f32_16x16x32_bf16(a0, ring[f & 7], acc[0][j], 0, 0, 0);
            acc[1][j] = __builtin_amdgcn_mfma_f32_16x16x32_bf16(a1, ring[f & 7], acc[1][j], 0, 0, 0);
            const int nf2 = (f + 8 < 16) ? f + 8 : 0;
            ring[f & 7] = gload(Wb5 + w5off(nf2));
        }
        drain8(ring);

        float* __restrict__ p = (float*)&lds[OFF_P];
        #pragma unroll
        for (int j = 0; j < 4; ++j) {
            const int col = wid * 64 + j * 16 + m_l;
            #pragma unroll
            for (int i = 0; i < 2; ++i)
                #pragma unroll
                for (int r = 0; r < 4; ++r)
                    p[(i*16 + quad*4 + r) * LD_P + col] = acc[i][j][r];
        }
    }
    __syncthreads();

    // ---- QP: one row per wave-iteration, contiguous float4 LDS reads -------
    const float b0 = bnd.x, b1 = bnd.y, b2 = bnd.z, b3 = bnd.w;
    const float* __restrict__ p = (const float*)&lds[OFF_P];
    #pragma unroll
    for (int i = 0; i < 8; ++i) {
        const int row = i * 4 + wid;
        const float4 pv = *(const float4*)&p[row * LD_P + lane * 4];
        float xs, wo, ys, ho;
        {
            const float px = pv.x, pw = pv.z;
            const float x0 = fmaxf(px, b0);
            const float g0 = fmaxf(pw, 1.0f);
            const float t  = 0.5f * (b2 - px - pw);
            const float xl = fminf(fmaxf(px + t, b0), b2 - 1.0f);
            const bool over = (x0 + g0) > b2;
            const float x = over ? xl : x0;
            const float g = over ? (b2 - xl) : g0;
            xs = x; wo = x + g;
        }
        {
            const float py = pv.y, ph = pv.w;
            const float x0 = fmaxf(py, b1);
            const float g0 = fmaxf(ph, 1.0f);
            const float t  = 0.5f * (b3 - py - ph);
            const float xl = fminf(fmaxf(py + t, b1), b3 - 1.0f);
            const bool over = (x0 + g0) > b3;
            const float x = over ? xl : x0;
            const float g = over ? (b3 - xl) : g0;
            ys = x; ho = x + g;
        }
        float4 o; o.x = xs; o.y = ys; o.z = wo; o.w = ho;
        ((float4*)out)[(size_t)(bm + row) * 64 + lane] = o;
    }
}

extern "C" void kernel_launch(void* const* d_in, const int* in_sizes, int n_in,
                              void* d_out, int out_size, void* d_ws, size_t ws_size,
                              hipStream_t stream) {
    const float* z      = (const float*)d_in[0];
    const float* bounds = (const float*)d_in[1];
    const float* W1 = (const float*)d_in[2];
    const float* c1 = (const float*)d_in[3];
    const float* W2 = (const float*)d_in[4];
    const float* c2 = (const float*)d_in[5];
    const float* W3 = (const float*)d_in[6];
    const float* c3 = (const float*)d_in[7];
    const float* W4 = (const float*)d_in[8];
    const float* c4 = (const float*)d_in[9];
    const float* W5 = (const float*)d_in[10];
    const float* c5 = (const float*)d_in[11];
    float* out = (float*)d_out;

    unsigned short* ws  = (unsigned short*)d_ws;
    unsigned short* Wt1 = ws;               // 512x544 = 278528
    unsigned short* Wt2 = Wt1 + 278528;     // 256x512 = 131072
    unsigned short* Wt3 = Wt2 + 131072;     // 128x256 = 32768
    unsigned short* Wt4 = Wt3 + 32768;      //  64x128 =  8192
    unsigned short* Wt5 = Wt4 + 8192;       // 256x64x2 = 32768 (hi/lo)

    pack_wt<<<dim3(1088, 5), 256, 0, stream>>>(
        W1, Wt1, W2, Wt2, W3, Wt3, W4, Wt4, W5, Wt5);
    fused_mlp_qp<<<dim3(MROWS / 32), 256, 0, stream>>>(
        z, bounds, Wt1, c1, Wt2, c2, Wt3, c3, Wt4, c4, Wt5, c5, out);
}